// Round 8
// baseline (610.730 us; speedup 1.0000x reference)
//
#include <hip/hip_runtime.h>

#define NN 50000
#define NE 500000
#define CAP 40          // max receiver degree; NN * P(Poisson(10) > 40) ~ 5e-9
#define NBLK 1024
#define NTHR 256
#define GSTRIDE (NBLK * NTHR)   // 262144
#define NWAVES (NBLK * 4)       // 4096

static __device__ __forceinline__ unsigned short f2b(float f) {
    union { float f; unsigned int u; } v; v.f = f;
    unsigned int u = v.u;
    return (unsigned short)((u + 0x7FFFu + ((u >> 16) & 1u)) >> 16);  // RNE
}
static __device__ __forceinline__ float b2f(unsigned short b) {
    union { unsigned int u; float f; } v; v.u = ((unsigned int)b) << 16;
    return v.f;
}
static __device__ __forceinline__ unsigned int pack2(float a, float b) {
    return (unsigned int)f2b(a) | ((unsigned int)f2b(b) << 16);
}

// Device-scope grid barrier: requires all NBLK blocks co-resident
// (guaranteed: 4 blocks/CU * 256 CUs, LDS 17.4KB, VGPR capped by launch_bounds).
static __device__ __forceinline__ void grid_barrier(int* bar, int target) {
    __syncthreads();
    if (threadIdx.x == 0) {
        __threadfence();  // release all block writes to device scope
        __hip_atomic_fetch_add(bar, 1, __ATOMIC_RELEASE, __HIP_MEMORY_SCOPE_AGENT);
        while (__hip_atomic_load(bar, __ATOMIC_RELAXED, __HIP_MEMORY_SCOPE_AGENT) < target)
            __builtin_amdgcn_s_sleep(8);
        (void)__hip_atomic_load(bar, __ATOMIC_ACQUIRE, __HIP_MEMORY_SCOPE_AGENT);
        __threadfence();
    }
    __syncthreads();
}

__global__ __launch_bounds__(NTHR, 4) void k_fused(
    const float* __restrict__ x, const int* __restrict__ ei,
    const float* __restrict__ elen, const float* __restrict__ wp,
    const float* __restrict__ rsc, const float* __restrict__ tsc,
    const float* __restrict__ scale_p, const float* __restrict__ wout,
    unsigned short* __restrict__ projb, float2* __restrict__ rst,
    int* __restrict__ cnt, int* __restrict__ ssend,
    unsigned int* __restrict__ scrh_u, int* __restrict__ bar,
    float* __restrict__ out)
{
    __shared__ float lwT[64 * 68];   // 17.4 KB (phase C epilogue weights)
    const int tid = threadIdx.x, bid = blockIdx.x;
    const int gtid = bid * NTHR + tid;
    const int lane = tid & 63, wid = tid >> 6;
    const int wgid = bid * 4 + wid;          // 0..NWAVES-1
    const int h = lane >> 4, q = lane & 15, grp = h << 4;

    // ================= phase A: zero cnt + proj + per-node scores ==========
    for (int i = gtid; i < NN; i += GSTRIDE) cnt[i] = 0;
    {
        const float4* wrow = (const float4*)(wp + (size_t)h * 4096);
        float4 r4 = *(const float4*)(rsc + h * 64 + q * 4);
        float4 t4 = *(const float4*)(tsc + h * 64 + q * 4);
        for (int g8 = wgid; g8 < NN / 8; g8 += NWAVES) {   // 6250 groups of 8 nodes
            int n0 = g8 * 8;
            float xv[8]; float4 a[8];
            #pragma unroll
            for (int j = 0; j < 8; ++j) {
                xv[j] = x[(n0 + j) * 64 + lane];
                a[j] = make_float4(0.f, 0.f, 0.f, 0.f);
            }
            #pragma unroll 4
            for (int k = 0; k < 64; ++k) {
                float4 w4 = wrow[k * 16 + q];
                #pragma unroll
                for (int j = 0; j < 8; ++j) {
                    float kx = __shfl(xv[j], k);
                    a[j].x += kx * w4.x; a[j].y += kx * w4.y;
                    a[j].z += kx * w4.z; a[j].w += kx * w4.w;
                }
            }
            #pragma unroll
            for (int j = 0; j < 8; ++j) {
                int n = n0 + j;
                float pr = a[j].x * r4.x + a[j].y * r4.y + a[j].z * r4.z + a[j].w * r4.w;
                float pt = a[j].x * t4.x + a[j].y * t4.y + a[j].z * t4.z + a[j].w * t4.w;
                #pragma unroll
                for (int m = 1; m < 16; m <<= 1) {
                    pr += __shfl_xor(pr, m);
                    pt += __shfl_xor(pt, m);
                }
                if (q == 0) rst[n * 4 + h] = make_float2(pr, pt);
                ushort4 pb;
                pb.x = f2b(a[j].x); pb.y = f2b(a[j].y);
                pb.z = f2b(a[j].z); pb.w = f2b(a[j].w);
                *((ushort4*)(projb + (size_t)n * 256 + lane * 4)) = pb;
            }
        }
    }
    grid_barrier(bar, NBLK);

    // ================= phase B: bucketize + sender-only exp records ========
    // Softmax is shift-invariant per receiver segment: alpha = e^{rs_s - d}/sum
    // (receiver score cancels) -> only the SENDER's rst row is gathered.
    {
        float sc = scale_p[0];
        const float* sf = (const float*)rst;    // node*8: {rs0,ts0,rs1,ts1,rs2,ts2,rs3,ts3}
        for (int e = gtid; e < NE; e += GSTRIDE) {
            int s = ei[e], r = ei[NE + e];
            float d = sc * elen[e];
            float4 ss0 = *(const float4*)(sf + s * 8);
            float4 ss1 = *(const float4*)(sf + s * 8 + 4);
            int slot = atomicAdd(&cnt[r], 1);
            if (slot < CAP) {
                int idx = r * CAP + slot;
                ssend[idx] = s;
                uint4 rec;
                rec.x = pack2(__expf(ss0.x - d), __expf(ss0.y));
                rec.y = pack2(__expf(ss0.z - d), __expf(ss0.w));
                rec.z = pack2(__expf(ss1.x - d), __expf(ss1.y));
                rec.w = pack2(__expf(ss1.z - d), __expf(ss1.w));
                *((uint4*)(scrh_u + (size_t)idx * 4)) = rec;
            }
        }
    }
    grid_barrier(bar, 2 * NBLK);

    // ================= phase C: gather-accumulate per receiver =============
    for (int i = tid; i < 4096; i += NTHR) {
        int f = i >> 6, g = i & 63;
        lwT[g * 68 + f] = wout[i];
    }
    __syncthreads();

#define ROWLD(SJ) (*(const ushort4*)(projb + ((size_t)(SJ) << 8) + (lane << 2)))
#define CONS(P, IDX) { \
    float cr = __shfl(erq, grp + (IDX)); \
    float ct = __shfl(etq, grp + (IDX)); \
    float p0 = b2f((P).x), p1 = b2f((P).y), p2 = b2f((P).z), p3 = b2f((P).w); \
    ar.x += cr * p0; ar.y += cr * p1; ar.z += cr * p2; ar.w += cr * p3; \
    at.x += ct * p0; at.y += ct * p1; at.z += ct * p2; at.w += ct * p3; }

    for (int n = wgid; n < NN; n += NWAVES) {
        float outv = x[n * 64 + lane];
        int cn = __hip_atomic_load(&cnt[n], __ATOMIC_RELAXED, __HIP_MEMORY_SCOPE_AGENT);
        if (cn > CAP) cn = CAP;
        float4 ar = {0.f,0.f,0.f,0.f}, at = {0.f,0.f,0.f,0.f};
        float srl = 0.f, stl = 0.f;
        if (cn > 0) {
            int rowb = n * CAP;
            for (int base = 0; base < cn; base += 12) {
                int bc = cn - base; if (bc > 12) bc = 12;
                // pad lanes clamp to the last valid slot: duplicate line
                // requests MSHR-merge (nearly free), coeffs forced to zero.
                int idx = rowb + base + ((q < bc) ? q : (bc - 1));
                int sq = __hip_atomic_load(&ssend[idx], __ATOMIC_RELAXED,
                                           __HIP_MEMORY_SCOPE_AGENT);
                unsigned cw = __hip_atomic_load(&scrh_u[(size_t)idx * 4 + h],
                                                __ATOMIC_RELAXED, __HIP_MEMORY_SCOPE_AGENT);
                float erq = 0.f, etq = 0.f;
                if (q < bc) {
                    erq = b2f((unsigned short)(cw & 0xffff));
                    etq = b2f((unsigned short)(cw >> 16));
                }
                srl += erq; stl += etq;
                ushort4 pA = ROWLD(__shfl(sq, 0));
                ushort4 pB = ROWLD(__shfl(sq, 1));
                ushort4 pC = ROWLD(__shfl(sq, 2));
                ushort4 pD = ROWLD(__shfl(sq, 3));
                ushort4 pE = ROWLD(__shfl(sq, 4));
                ushort4 pF = ROWLD(__shfl(sq, 5));
                ushort4 pG = ROWLD(__shfl(sq, 6));
                ushort4 pH = ROWLD(__shfl(sq, 7));
                ushort4 pI = ROWLD(__shfl(sq, 8));
                ushort4 pJ = ROWLD(__shfl(sq, 9));
                ushort4 pK = ROWLD(__shfl(sq, 10));
                ushort4 pL = ROWLD(__shfl(sq, 11));
                CONS(pA, 0)  CONS(pB, 1)  CONS(pC, 2)  CONS(pD, 3)
                CONS(pE, 4)  CONS(pF, 5)  CONS(pG, 6)  CONS(pH, 7)
                CONS(pI, 8)  CONS(pJ, 9)  CONS(pK, 10) CONS(pL, 11)
            }
            #pragma unroll
            for (int m = 1; m < 16; m <<= 1) {
                srl += __shfl_xor(srl, m);
                stl += __shfl_xor(stl, m);
            }
            float isr = 1.0f / srl, ist = 1.0f / stl;
            ushort4 pr = ROWLD(n);
            ar.x = isr * ar.x + ist * at.x - 2.f * b2f(pr.x);
            ar.y = isr * ar.y + ist * at.y - 2.f * b2f(pr.y);
            ar.z = isr * ar.z + ist * at.z - 2.f * b2f(pr.z);
            ar.w = isr * ar.w + ist * at.w - 2.f * b2f(pr.w);
        }
        // head mean (lanes ^16, ^32), scale 1/4
        ar.x += __shfl_xor(ar.x, 16); ar.y += __shfl_xor(ar.y, 16);
        ar.z += __shfl_xor(ar.z, 16); ar.w += __shfl_xor(ar.w, 16);
        ar.x += __shfl_xor(ar.x, 32); ar.y += __shfl_xor(ar.y, 32);
        ar.z += __shfl_xor(ar.z, 32); ar.w += __shfl_xor(ar.w, 32);
        float4 m4 = make_float4(0.25f * ar.x, 0.25f * ar.y, 0.25f * ar.z, 0.25f * ar.w);

        // out[n,g] = x[n,g] + sum_f m[f] * w_out[f,g];  g = lane
        const float* wTg = lwT + lane * 68;
        #pragma unroll
        for (int j = 0; j < 16; ++j) {
            float4 wv = *(const float4*)(wTg + j * 4);
            outv += __shfl(m4.x, j) * wv.x + __shfl(m4.y, j) * wv.y
                  + __shfl(m4.z, j) * wv.z + __shfl(m4.w, j) * wv.w;
        }
        out[n * 64 + lane] = outv;
    }
#undef ROWLD
#undef CONS
}

extern "C" void kernel_launch(void* const* d_in, const int* in_sizes, int n_in,
                              void* d_out, int out_size, void* d_ws, size_t ws_size,
                              hipStream_t stream) {
    const float* x       = (const float*)d_in[0];
    const int*   ei      = (const int*)d_in[1];
    const float* elen    = (const float*)d_in[3];
    const float* wp      = (const float*)d_in[4];
    const float* rsc     = (const float*)d_in[5];
    const float* tsc     = (const float*)d_in[6];
    const float* scale_p = (const float*)d_in[7];
    const float* wout    = (const float*)d_in[8];
    float* out = (float*)d_out;

    char* ws = (char*)d_ws;
    size_t off = 0;
    auto alloc = [&](size_t bytes) {
        void* p = ws + off;
        off = (off + bytes + 255) & ~(size_t)255;
        return p;
    };
    unsigned short* projb = (unsigned short*)alloc((size_t)NN * 256 * 2);   // 25.6 MB
    float2*       rst    = (float2*)alloc((size_t)NN * 4 * 8);              // 1.6 MB
    int*          cnt    = (int*)alloc((size_t)NN * 4);
    int*          ssend  = (int*)alloc(((size_t)NN * CAP + 64) * 4);        // 8 MB
    unsigned int* scrh   = (unsigned int*)alloc(((size_t)NN * CAP + 64) * 16); // 32 MB
    int*          bar    = (int*)alloc(256);

    hipMemsetAsync(bar, 0, 16, stream);
    k_fused<<<NBLK, NTHR, 0, stream>>>(x, ei, elen, wp, rsc, tsc, scale_p, wout,
                                       projb, rst, cnt, ssend, scrh, bar, out);
}

// Round 9
// 257.103 us; speedup vs baseline: 2.3754x; 2.3754x over previous
//
#include <hip/hip_runtime.h>

#define NN 50000
#define NE 500000
#define CAP 40   // max receiver degree; NN * P(Poisson(10) > 40) ~ 5e-9

static __device__ __forceinline__ unsigned short f2b(float f) {
    union { float f; unsigned int u; } v; v.f = f;
    unsigned int u = v.u;
    return (unsigned short)((u + 0x7FFFu + ((u >> 16) & 1u)) >> 16);  // RNE
}
static __device__ __forceinline__ float b2f(unsigned short b) {
    union { unsigned int u; float f; } v; v.u = ((unsigned int)b) << 16;
    return v.f;
}
static __device__ __forceinline__ unsigned int pack2(float a, float b) {
    return (unsigned int)f2b(a) | ((unsigned int)f2b(b) << 16);
}

static __device__ __forceinline__ void finish_node(
    int n, float4 a, float4 r4, float4 t4, int lane, int h, int gq,
    float2* __restrict__ rst, unsigned short* __restrict__ projb)
{
    float pr = a.x * r4.x + a.y * r4.y + a.z * r4.z + a.w * r4.w;
    float pt = a.x * t4.x + a.y * t4.y + a.z * t4.z + a.w * t4.w;
    #pragma unroll
    for (int m = 1; m < 16; m <<= 1) {
        pr += __shfl_xor(pr, m);
        pt += __shfl_xor(pt, m);
    }
    if (gq == 0) rst[n * 4 + h] = make_float2(pr, pt);
    ushort4 pb;
    pb.x = f2b(a.x); pb.y = f2b(a.y); pb.z = f2b(a.z); pb.w = f2b(a.w);
    *((ushort4*)(projb + (size_t)n * 256 + lane * 4)) = pb;
}

// K1: proj (4 nodes per wave, w_proj in LDS) + per-node {rs,ts} scores.
// Also zeroes cnt[] (consumed by the NEXT dispatch in stream order).
__global__ __launch_bounds__(256) void k_proj(
    const float* __restrict__ x, const float* __restrict__ wp,
    const float* __restrict__ rsc, const float* __restrict__ tsc,
    unsigned short* __restrict__ projb, float2* __restrict__ rst,
    int* __restrict__ cnt)
{
    __shared__ float lw[4 * 64 * 64];   // 64 KB
    int tid = threadIdx.x;
    int gtid = blockIdx.x * 256 + tid;
    if (gtid < NN) cnt[gtid] = 0;
    for (int i = tid; i < 4096; i += 256)
        ((float4*)lw)[i] = ((const float4*)wp)[i];
    __syncthreads();

    int lane = tid & 63, wid = tid >> 6;
    int h = lane >> 4, gq = lane & 15;
    const float4* wrow = (const float4*)(lw + h * 4096);
    float4 r4 = *(const float4*)(rsc + h * 64 + gq * 4);
    float4 t4 = *(const float4*)(tsc + h * 64 + gq * 4);

    int gw = blockIdx.x * 4 + wid;   // 12500 waves, 4 nodes each
    int n0 = gw * 4;
    if (n0 >= NN) return;
    float xv0 = x[(n0 + 0) * 64 + lane];
    float xv1 = x[(n0 + 1) * 64 + lane];
    float xv2 = x[(n0 + 2) * 64 + lane];
    float xv3 = x[(n0 + 3) * 64 + lane];
    float4 a0 = {0,0,0,0}, a1 = {0,0,0,0}, a2 = {0,0,0,0}, a3 = {0,0,0,0};
    #pragma unroll 4
    for (int k = 0; k < 64; ++k) {
        float4 w4 = wrow[k * 16 + gq];
        float k0 = __shfl(xv0, k), k1 = __shfl(xv1, k);
        float k2 = __shfl(xv2, k), k3 = __shfl(xv3, k);
        a0.x += k0 * w4.x; a0.y += k0 * w4.y; a0.z += k0 * w4.z; a0.w += k0 * w4.w;
        a1.x += k1 * w4.x; a1.y += k1 * w4.y; a1.z += k1 * w4.z; a1.w += k1 * w4.w;
        a2.x += k2 * w4.x; a2.y += k2 * w4.y; a2.z += k2 * w4.z; a2.w += k2 * w4.w;
        a3.x += k3 * w4.x; a3.y += k3 * w4.y; a3.z += k3 * w4.z; a3.w += k3 * w4.w;
    }
    finish_node(n0 + 0, a0, r4, t4, lane, h, gq, rst, projb);
    finish_node(n0 + 1, a1, r4, t4, lane, h, gq, rst, projb);
    finish_node(n0 + 2, a2, r4, t4, lane, h, gq, rst, projb);
    finish_node(n0 + 3, a3, r4, t4, lane, h, gq, rst, projb);
}

// K2: bucketize + SENDER-ONLY exp records (softmax shift-invariance:
// the receiver score cancels in alpha, so only sender's 32B row is gathered).
__global__ __launch_bounds__(256) void k_bucket(
    const int* __restrict__ ei, const float* __restrict__ elen,
    const float* __restrict__ rst_f,   // float view: node*8 = {rs0,ts0,...,rs3,ts3}
    const float* __restrict__ scale_p,
    int* __restrict__ cnt, int* __restrict__ ssend, uint4* __restrict__ scrh)
{
    int e = blockIdx.x * 256 + threadIdx.x;
    if (e >= NE) return;
    int s = ei[e], r = ei[NE + e];
    float d = scale_p[0] * elen[e];
    float4 ss0 = *(const float4*)(rst_f + s * 8);
    float4 ss1 = *(const float4*)(rst_f + s * 8 + 4);
    int slot = atomicAdd(&cnt[r], 1);
    if (slot >= CAP) return;
    int idx = r * CAP + slot;
    ssend[idx] = s;
    uint4 rec;
    rec.x = pack2(__expf(ss0.x - d), __expf(ss0.y));   // head 0: {er, et}
    rec.y = pack2(__expf(ss0.z - d), __expf(ss0.w));   // head 1
    rec.z = pack2(__expf(ss1.x - d), __expf(ss1.y));   // head 2
    rec.w = pack2(__expf(ss1.z - d), __expf(ss1.w));   // head 3
    scrh[idx] = rec;
}

// K3: one wave per receiver. ZERO LDS ops in the hot loop: sq via wave-uniform
// loads, coeffs via 16-lane-uniform loads (so no denominator reduce needed),
// 16-deep batched row gathers, head-mean via 8 shfls, bf16 msg row out.
__global__ __launch_bounds__(256) void k_msg(
    const unsigned short* __restrict__ projb,
    const int* __restrict__ cnt, const int* __restrict__ ssend,
    const unsigned int* __restrict__ scrh_u,   // uint view: record idx*4 + h
    unsigned short* __restrict__ msg)
{
    int tid = threadIdx.x;
    int lane = tid & 63, wid = tid >> 6;
    int h = lane >> 4, q = lane & 15;
    int n = blockIdx.x * 4 + wid;   // 12500 * 4 = NN exact

    int cn = cnt[n]; if (cn > CAP) cn = CAP;
    ushort4 own = *(const ushort4*)(projb + ((size_t)n << 8) + (lane << 2));

    float4 ar = {0.f,0.f,0.f,0.f}, at = {0.f,0.f,0.f,0.f};
    float srl = 0.f, stl = 0.f;

    if (cn > 0) {
        int rowb = n * CAP;
        for (int base = 0; base < cn; base += 16) {
            int bc = cn - base; if (bc > 16) bc = 16;
            unsigned int cw[16]; int sq[16]; ushort4 pr[16];
            #pragma unroll
            for (int j = 0; j < 16; ++j) {
                int jj = (j < bc) ? j : (bc - 1);     // clamp: dup lines MSHR-merge
                int idx = rowb + base + jj;
                cw[j] = scrh_u[(size_t)idx * 4 + h];  // 16-lane-uniform, L1-hot
                sq[j] = ssend[idx];                   // wave-uniform, 1 line
            }
            #pragma unroll
            for (int j = 0; j < 16; ++j)
                pr[j] = *(const ushort4*)(projb + ((size_t)sq[j] << 8) + (lane << 2));
            #pragma unroll
            for (int j = 0; j < 16; ++j) {
                float er = 0.f, et = 0.f;
                if (j < bc) {
                    er = b2f((unsigned short)(cw[j] & 0xffffu));
                    et = b2f((unsigned short)(cw[j] >> 16));
                }
                srl += er; stl += et;    // uniform within head group: no reduce
                float p0 = b2f(pr[j].x), p1 = b2f(pr[j].y);
                float p2 = b2f(pr[j].z), p3 = b2f(pr[j].w);
                ar.x += er * p0; ar.y += er * p1; ar.z += er * p2; ar.w += er * p3;
                at.x += et * p0; at.y += et * p1; at.z += et * p2; at.w += et * p3;
            }
        }
        float isr = 1.0f / srl, ist = 1.0f / stl;
        ar.x = isr * ar.x + ist * at.x - 2.f * b2f(own.x);
        ar.y = isr * ar.y + ist * at.y - 2.f * b2f(own.y);
        ar.z = isr * ar.z + ist * at.z - 2.f * b2f(own.z);
        ar.w = isr * ar.w + ist * at.w - 2.f * b2f(own.w);
    }
    // head mean (lanes ^16, ^32), scale 1/4
    ar.x += __shfl_xor(ar.x, 16); ar.y += __shfl_xor(ar.y, 16);
    ar.z += __shfl_xor(ar.z, 16); ar.w += __shfl_xor(ar.w, 16);
    ar.x += __shfl_xor(ar.x, 32); ar.y += __shfl_xor(ar.y, 32);
    ar.z += __shfl_xor(ar.z, 32); ar.w += __shfl_xor(ar.w, 32);
    if (h == 0) {
        ushort4 mb;
        mb.x = f2b(0.25f * ar.x); mb.y = f2b(0.25f * ar.y);
        mb.z = f2b(0.25f * ar.z); mb.w = f2b(0.25f * ar.w);
        *((ushort4*)(msg + (size_t)n * 64 + q * 4)) = mb;   // 128B coalesced row
    }
}

// K4: out = x + msg @ w_out. Lane = output column g; each lane holds the
// w_out column in 64 VGPRs (zero LDS); msg rows read as uniform loads.
__global__ __launch_bounds__(256) void k_out(
    const float* __restrict__ x, const unsigned short* __restrict__ msg,
    const float* __restrict__ wout, float* __restrict__ out)
{
    int lane = threadIdx.x & 63, wid = threadIdx.x >> 6;
    float wreg[64];
    #pragma unroll
    for (int f = 0; f < 64; ++f) wreg[f] = wout[f * 64 + lane];  // coalesced

    int n0 = (blockIdx.x * 4 + wid) * 16;
    for (int u = 0; u < 16; ++u) {
        int n = n0 + u;
        if (n >= NN) return;
        float outv = x[(size_t)n * 64 + lane];
        #pragma unroll
        for (int j = 0; j < 8; ++j) {
            uint2 mm = *(const uint2*)(msg + (size_t)n * 64 + j * 8);  // uniform
            float m0 = b2f((unsigned short)(mm.x & 0xffffu));
            float m1 = b2f((unsigned short)(mm.x >> 16));
            float m2 = b2f((unsigned short)(mm.y & 0xffffu));
            float m3 = b2f((unsigned short)(mm.y >> 16));
            outv += m0 * wreg[j * 8 + 0] + m1 * wreg[j * 8 + 1]
                  + m2 * wreg[j * 8 + 2] + m3 * wreg[j * 8 + 3];
            uint2 nn2 = *(const uint2*)(msg + (size_t)n * 64 + j * 8 + 4);
            float m4 = b2f((unsigned short)(nn2.x & 0xffffu));
            float m5 = b2f((unsigned short)(nn2.x >> 16));
            float m6 = b2f((unsigned short)(nn2.y & 0xffffu));
            float m7 = b2f((unsigned short)(nn2.y >> 16));
            outv += m4 * wreg[j * 8 + 4] + m5 * wreg[j * 8 + 5]
                  + m6 * wreg[j * 8 + 6] + m7 * wreg[j * 8 + 7];
        }
        out[(size_t)n * 64 + lane] = outv;
    }
}

extern "C" void kernel_launch(void* const* d_in, const int* in_sizes, int n_in,
                              void* d_out, int out_size, void* d_ws, size_t ws_size,
                              hipStream_t stream) {
    const float* x       = (const float*)d_in[0];
    const int*   ei      = (const int*)d_in[1];
    const float* elen    = (const float*)d_in[3];
    const float* wp      = (const float*)d_in[4];
    const float* rsc     = (const float*)d_in[5];
    const float* tsc     = (const float*)d_in[6];
    const float* scale_p = (const float*)d_in[7];
    const float* wout    = (const float*)d_in[8];
    float* out = (float*)d_out;

    char* ws = (char*)d_ws;
    size_t off = 0;
    auto alloc = [&](size_t bytes) {
        void* p = ws + off;
        off = (off + bytes + 255) & ~(size_t)255;
        return p;
    };
    unsigned short* projb = (unsigned short*)alloc((size_t)NN * 256 * 2);   // 25.6 MB
    float2*         rst   = (float2*)alloc((size_t)NN * 4 * 8);             // 1.6 MB
    int*            cnt   = (int*)alloc((size_t)NN * 4);
    int*            ssend = (int*)alloc(((size_t)NN * CAP + 64) * 4);       // 8 MB
    uint4*          scrh  = (uint4*)alloc(((size_t)NN * CAP + 64) * 16);    // 32 MB
    unsigned short* msg   = (unsigned short*)alloc((size_t)NN * 64 * 2);    // 6.4 MB

    k_proj<<<3125, 256, 0, stream>>>(x, wp, rsc, tsc, projb, rst, cnt);
    k_bucket<<<(NE + 255) / 256, 256, 0, stream>>>(ei, elen, (const float*)rst,
                                                   scale_p, cnt, ssend, scrh);
    k_msg<<<12500, 256, 0, stream>>>(projb, cnt, ssend,
                                     (const unsigned int*)scrh, msg);
    k_out<<<(NN + 63) / 64, 256, 0, stream>>>(x, msg, wout, out);
}